// Round 1
// baseline (1407.205 us; speedup 1.0000x reference)
//
#include <hip/hip_runtime.h>
#include <math.h>

#define NN 100000
#define EE 1600000
#define ET (EE + NN)   // edges + self loops
#define F1 128         // H*C layer1
#define NH 16
#define F2 19

// ---------------- CSR build ----------------
__global__ __launch_bounds__(256) void deg_kernel(const int* __restrict__ dst, int* __restrict__ deg) {
  int e = blockIdx.x * 256 + threadIdx.x;
  if (e >= ET) return;
  int d = (e < EE) ? dst[e] : (e - EE);
  atomicAdd(&deg[d], 1);
}

__global__ __launch_bounds__(1024) void scan_kernel(const int* __restrict__ deg, int* __restrict__ offs) {
  __shared__ int wsum[16];
  __shared__ int wpre[16];
  const int tid = threadIdx.x;
  const int lane = tid & 63, wid = tid >> 6;
  int running = 0;
  for (int base = 0; base < NN; base += 1024) {
    int i = base + tid;
    int v = (i < NN) ? deg[i] : 0;
    int x = v;
    #pragma unroll
    for (int off = 1; off < 64; off <<= 1) {
      int t = __shfl_up(x, off, 64);
      if (lane >= off) x += t;
    }
    if (lane == 63) wsum[wid] = x;
    __syncthreads();
    if (tid < 16) {
      int y = wsum[tid];
      #pragma unroll
      for (int off = 1; off < 16; off <<= 1) {
        int t = __shfl_up(y, off, 16);
        if ((tid & 15) >= off) y += t;
      }
      wpre[tid] = y - wsum[tid];   // exclusive prefix of wave sums
    }
    __syncthreads();
    int incl = x + wpre[wid];
    if (i < NN) offs[i] = running + incl - v;
    running += wpre[15] + wsum[15];
    __syncthreads();   // protect wsum/wpre before next chunk overwrites
  }
  if (tid == 0) offs[NN] = running;
}

__global__ __launch_bounds__(256) void fill_kernel(const int* __restrict__ src, const int* __restrict__ dst,
                                                   const int* __restrict__ offs, int* __restrict__ cnt,
                                                   int* __restrict__ csr) {
  int e = blockIdx.x * 256 + threadIdx.x;
  if (e >= ET) return;
  int d, s;
  if (e < EE) { d = dst[e]; s = src[e]; } else { d = e - EE; s = e - EE; }
  int pos = offs[d] + atomicAdd(&cnt[d], 1);
  csr[pos] = s;
}

// ---------------- GEMM1: h1 = x @ W1  (M=1e5, K=1024, N=128), fp32 ----------------
__global__ __launch_bounds__(256) void gemm1_kernel(const float* __restrict__ X, const float* __restrict__ W,
                                                    float* __restrict__ H1, int M) {
  __shared__ float As[16][132];   // [k][m], padded
  __shared__ float Bs[16][128];   // [k][n]
  const int tid = threadIdx.x;
  const int m0 = blockIdx.x * 128;
  const int rowg = (tid >> 4) * 8;
  const int colg = (tid & 15) * 8;
  const int ar = tid >> 2;
  const int ac = (tid & 3) * 4;
  const int bk = tid >> 4;
  const int bc = (tid & 15) * 8;
  float acc[8][8];
  #pragma unroll
  for (int i = 0; i < 8; ++i)
    #pragma unroll
    for (int j = 0; j < 8; ++j) acc[i][j] = 0.f;

  for (int kt = 0; kt < 1024; kt += 16) {
    #pragma unroll
    for (int half = 0; half < 2; ++half) {
      int row = ar + half * 64;
      int grow = m0 + row; if (grow > M - 1) grow = M - 1;
      const float4 v = *reinterpret_cast<const float4*>(&X[(size_t)grow * 1024 + kt + ac]);
      As[ac + 0][row] = v.x; As[ac + 1][row] = v.y; As[ac + 2][row] = v.z; As[ac + 3][row] = v.w;
    }
    {
      const float4 v0 = *reinterpret_cast<const float4*>(&W[(size_t)(kt + bk) * 128 + bc]);
      const float4 v1 = *reinterpret_cast<const float4*>(&W[(size_t)(kt + bk) * 128 + bc + 4]);
      *reinterpret_cast<float4*>(&Bs[bk][bc]) = v0;
      *reinterpret_cast<float4*>(&Bs[bk][bc + 4]) = v1;
    }
    __syncthreads();
    #pragma unroll
    for (int k = 0; k < 16; ++k) {
      float a[8], b[8];
      #pragma unroll
      for (int i = 0; i < 8; ++i) a[i] = As[k][rowg + i];
      #pragma unroll
      for (int j = 0; j < 8; ++j) b[j] = Bs[k][colg + j];
      #pragma unroll
      for (int i = 0; i < 8; ++i)
        #pragma unroll
        for (int j = 0; j < 8; ++j) acc[i][j] += a[i] * b[j];
    }
    __syncthreads();
  }
  #pragma unroll
  for (int i = 0; i < 8; ++i) {
    int row = m0 + rowg + i;
    if (row < M) {
      float4 v0 = make_float4(acc[i][0], acc[i][1], acc[i][2], acc[i][3]);
      float4 v1 = make_float4(acc[i][4], acc[i][5], acc[i][6], acc[i][7]);
      *reinterpret_cast<float4*>(&H1[(size_t)row * 128 + colg]) = v0;
      *reinterpret_cast<float4*>(&H1[(size_t)row * 128 + colg + 4]) = v1;
    }
  }
}

// ---------------- attention scalars layer 1 ----------------
__global__ __launch_bounds__(256) void a1_kernel(const float* __restrict__ h1, const float* __restrict__ att_s,
                                                 const float* __restrict__ att_d, float* __restrict__ a_src,
                                                 float* __restrict__ a_dst) {
  int idx = blockIdx.x * 256 + threadIdx.x;   // n*16 + h
  if (idx >= NN * NH) return;
  int h = idx & 15;
  const float* hp = &h1[(size_t)idx * 8];
  float s = 0.f, d = 0.f;
  #pragma unroll
  for (int c = 0; c < 8; ++c) {
    float v = hp[c];
    s += v * att_s[h * 8 + c];
    d += v * att_d[h * 8 + c];
  }
  a_src[idx] = s; a_dst[idx] = d;
}

// ---------------- layer1 aggregation: online softmax + ELU epilogue ----------------
__global__ __launch_bounds__(128) void agg1_kernel(const float* __restrict__ h1, const float* __restrict__ a_src,
                                                   const float* __restrict__ a_dst, const int* __restrict__ offs,
                                                   const int* __restrict__ csr, const float* __restrict__ b1,
                                                   float* __restrict__ act1) {
  int n = blockIdx.x;
  int t = threadIdx.x;        // channel 0..127
  int h = t >> 3;
  float adst = a_dst[n * NH + h];
  int beg = offs[n], end = offs[n + 1];
  float m = -INFINITY, l = 0.f, acc = 0.f;
  for (int e = beg; e < end; ++e) {
    int s = csr[e];
    float a = a_src[s * NH + h] + adst;
    a = a > 0.f ? a : 0.2f * a;
    float nm = fmaxf(m, a);
    float sc = __expf(m - nm);
    float w = __expf(a - nm);
    l = l * sc + w;
    acc = acc * sc + w * h1[(size_t)s * 128 + t];
    m = nm;
  }
  float o = acc / (l + 1e-16f) + b1[t];
  act1[(size_t)n * 128 + t] = o > 0.f ? o : expm1f(o);
}

// ---------------- GEMM2: h2 = act1 @ W2  (K=128, N=19) ----------------
__global__ __launch_bounds__(256) void gemm2_kernel(const float* __restrict__ A, const float* __restrict__ W2,
                                                    float* __restrict__ H2) {
  __shared__ float Ws[128 * 19];
  for (int i = threadIdx.x; i < 128 * 19; i += 256) Ws[i] = W2[i];
  __syncthreads();
  int idx = blockIdx.x * 256 + threadIdx.x;
  if (idx >= NN * F2) return;
  int row = idx / F2, col = idx % F2;
  const float* a = &A[(size_t)row * 128];
  float s = 0.f;
  #pragma unroll 8
  for (int k = 0; k < 128; ++k) s += a[k] * Ws[k * F2 + col];
  H2[idx] = s;
}

// ---------------- attention scalars layer 2 ----------------
__global__ __launch_bounds__(256) void a2_kernel(const float* __restrict__ h2, const float* __restrict__ att_s,
                                                 const float* __restrict__ att_d, float* __restrict__ a_src,
                                                 float* __restrict__ a_dst) {
  int n = blockIdx.x * 256 + threadIdx.x;
  if (n >= NN) return;
  const float* hp = &h2[(size_t)n * F2];
  float s = 0.f, d = 0.f;
  #pragma unroll
  for (int c = 0; c < F2; ++c) {
    float v = hp[c];
    s += v * att_s[c];
    d += v * att_d[c];
  }
  a_src[n] = s; a_dst[n] = d;
}

// ---------------- layer2 aggregation + bias + log_softmax ----------------
__global__ __launch_bounds__(64) void agg2_kernel(const float* __restrict__ h2, const float* __restrict__ a_src,
                                                  const float* __restrict__ a_dst, const int* __restrict__ offs,
                                                  const int* __restrict__ csr, const float* __restrict__ b2,
                                                  float* __restrict__ out) {
  int n = blockIdx.x;
  int t = threadIdx.x;
  bool act = t < F2;
  float adst = a_dst[n];
  int beg = offs[n], end = offs[n + 1];
  float m = -INFINITY, l = 0.f, acc = 0.f;
  for (int e = beg; e < end; ++e) {
    int s = csr[e];
    float a = a_src[s] + adst;
    a = a > 0.f ? a : 0.2f * a;
    float nm = fmaxf(m, a);
    float sc = __expf(m - nm);
    float w = __expf(a - nm);
    l = l * sc + w;
    float hv = act ? h2[(size_t)s * F2 + t] : 0.f;
    acc = acc * sc + w * hv;
    m = nm;
  }
  float o = acc / (l + 1e-16f) + (act ? b2[t] : 0.f);
  // log_softmax over the 19 channels (lanes 0..18; reduce over 32-lane group)
  float v = act ? o : -INFINITY;
  float mx = v;
  #pragma unroll
  for (int off = 16; off >= 1; off >>= 1) mx = fmaxf(mx, __shfl_xor(mx, off, 64));
  float se = act ? __expf(v - mx) : 0.f;
  float sum = se;
  #pragma unroll
  for (int off = 16; off >= 1; off >>= 1) sum += __shfl_xor(sum, off, 64);
  if (act) out[(size_t)n * F2 + t] = (o - mx) - logf(sum);
}

extern "C" void kernel_launch(void* const* d_in, const int* in_sizes, int n_in,
                              void* d_out, int out_size, void* d_ws, size_t ws_size,
                              hipStream_t stream) {
  const float* x   = (const float*)d_in[0];
  const int* ei    = (const int*)d_in[1];
  const float* W1  = (const float*)d_in[2];
  const float* as1 = (const float*)d_in[3];
  const float* ad1 = (const float*)d_in[4];
  const float* b1  = (const float*)d_in[5];
  const float* W2  = (const float*)d_in[6];
  const float* as2 = (const float*)d_in[7];
  const float* ad2 = (const float*)d_in[8];
  const float* b2  = (const float*)d_in[9];
  float* out = (float*)d_out;

  const int* srcp = ei;
  const int* dstp = ei + EE;

  char* p = (char*)d_ws;
  auto alloc = [&](size_t bytes) { char* r = p; p += (bytes + 255) & ~(size_t)255; return r; };
  float* h1    = (float*)alloc((size_t)NN * F1 * 4);
  float* act1  = (float*)alloc((size_t)NN * F1 * 4);
  float* a_s1  = (float*)alloc((size_t)NN * NH * 4);
  float* a_d1  = (float*)alloc((size_t)NN * NH * 4);
  float* h2    = (float*)alloc((size_t)NN * F2 * 4);
  float* a_s2  = (float*)alloc((size_t)NN * 4);
  float* a_d2  = (float*)alloc((size_t)NN * 4);
  int*   deg   = (int*)alloc((size_t)NN * 4);
  int*   offs  = (int*)alloc((size_t)(NN + 1) * 4);
  int*   cnt   = (int*)alloc((size_t)NN * 4);
  int*   csr   = (int*)alloc((size_t)ET * 4);

  hipMemsetAsync(deg, 0, (size_t)NN * 4, stream);
  hipMemsetAsync(cnt, 0, (size_t)NN * 4, stream);

  int eb = (ET + 255) / 256;
  deg_kernel<<<eb, 256, 0, stream>>>(dstp, deg);
  scan_kernel<<<1, 1024, 0, stream>>>(deg, offs);
  fill_kernel<<<eb, 256, 0, stream>>>(srcp, dstp, offs, cnt, csr);

  gemm1_kernel<<<(NN + 127) / 128, 256, 0, stream>>>(x, W1, h1, NN);
  a1_kernel<<<(NN * NH + 255) / 256, 256, 0, stream>>>(h1, as1, ad1, a_s1, a_d1);
  agg1_kernel<<<NN, 128, 0, stream>>>(h1, a_s1, a_d1, offs, csr, b1, act1);

  gemm2_kernel<<<(NN * F2 + 255) / 256, 256, 0, stream>>>(act1, W2, h2);
  a2_kernel<<<(NN + 255) / 256, 256, 0, stream>>>(h2, as2, ad2, a_s2, a_d2);
  agg2_kernel<<<NN, 64, 0, stream>>>(h2, a_s2, a_d2, offs, csr, b2, out);
}

// Round 2
// 1248.293 us; speedup vs baseline: 1.1273x; 1.1273x over previous
//
#include <hip/hip_runtime.h>
#include <math.h>

#define NN 100000
#define EE 1600000
#define ET (EE + NN)   // edges + self loops
#define F1 128         // H*C layer1
#define NH 16
#define F2 19

typedef __bf16 bf16x8 __attribute__((ext_vector_type(8)));
typedef float f32x4 __attribute__((ext_vector_type(4)));

#define LDST 40   // LDS row stride in bf16 elems: 80B -> 16B aligned, 2-way bank alias (free)

// ---------------- CSR build ----------------
__global__ __launch_bounds__(256) void deg_kernel(const int* __restrict__ dst, int* __restrict__ deg) {
  int e = blockIdx.x * 256 + threadIdx.x;
  if (e >= ET) return;
  int d = (e < EE) ? dst[e] : (e - EE);
  atomicAdd(&deg[d], 1);
}

__global__ __launch_bounds__(1024) void scan_kernel(const int* __restrict__ deg, int* __restrict__ offs) {
  __shared__ int wsum[16];
  __shared__ int wpre[16];
  const int tid = threadIdx.x;
  const int lane = tid & 63, wid = tid >> 6;
  int running = 0;
  for (int base = 0; base < NN; base += 1024) {
    int i = base + tid;
    int v = (i < NN) ? deg[i] : 0;
    int x = v;
    #pragma unroll
    for (int off = 1; off < 64; off <<= 1) {
      int t = __shfl_up(x, off, 64);
      if (lane >= off) x += t;
    }
    if (lane == 63) wsum[wid] = x;
    __syncthreads();
    if (tid < 16) {
      int y = wsum[tid];
      #pragma unroll
      for (int off = 1; off < 16; off <<= 1) {
        int t = __shfl_up(y, off, 16);
        if ((tid & 15) >= off) y += t;
      }
      wpre[tid] = y - wsum[tid];
    }
    __syncthreads();
    int incl = x + wpre[wid];
    if (i < NN) offs[i] = running + incl - v;
    running += wpre[15] + wsum[15];
    __syncthreads();
  }
  if (tid == 0) offs[NN] = running;
}

__global__ __launch_bounds__(256) void fill_kernel(const int* __restrict__ src, const int* __restrict__ dst,
                                                   const int* __restrict__ offs, int* __restrict__ cnt,
                                                   int* __restrict__ csr) {
  int e = blockIdx.x * 256 + threadIdx.x;
  if (e >= ET) return;
  int d, s;
  if (e < EE) { d = dst[e]; s = src[e]; } else { d = e - EE; s = e - EE; }
  int pos = offs[d] + atomicAdd(&cnt[d], 1);
  csr[pos] = s;
}

// ---------------- W1 split+transpose: Wt_h/Wt_l [128][1024] bf16 ----------------
__global__ __launch_bounds__(256) void wsplit_kernel(const float* __restrict__ W, __bf16* __restrict__ Wth,
                                                     __bf16* __restrict__ Wtl) {
  int idx = blockIdx.x * 256 + threadIdx.x;   // k*128 + n
  if (idx >= 1024 * 128) return;
  int k = idx >> 7, n = idx & 127;
  float v = W[idx];
  __bf16 h = (__bf16)v;
  __bf16 l = (__bf16)(v - (float)h);
  Wth[(size_t)n * 1024 + k] = h;
  Wtl[(size_t)n * 1024 + k] = l;
}

// ---------------- GEMM1: h1 = x @ W1 via bf16x3 MFMA (M=1e5, K=1024, N=128) ----------------
__global__ __launch_bounds__(256) void gemm1_mfma(const float* __restrict__ X, const __bf16* __restrict__ Wth,
                                                  const __bf16* __restrict__ Wtl, float* __restrict__ H1, int M) {
  __shared__ __bf16 Ah[128 * LDST];
  __shared__ __bf16 Al[128 * LDST];
  __shared__ __bf16 Bh[128 * LDST];
  __shared__ __bf16 Bl[128 * LDST];
  const int tid = threadIdx.x;
  const int m0 = blockIdx.x * 128;
  const int wv = tid >> 6, lane = tid & 63;
  const int lrow = lane & 15, quad = lane >> 4;
  // staging: thread t handles row sr, k-halfchunk sk (16 elems)
  const int sr = tid >> 1;
  const int sk = (tid & 1) * 16;
  int grow = m0 + sr; if (grow > M - 1) grow = M - 1;
  const float* xrow = &X[(size_t)grow * 1024];
  const __bf16* wthr = &Wth[(size_t)sr * 1024];
  const __bf16* wtlr = &Wtl[(size_t)sr * 1024];

  f32x4 acc[2][8];
  #pragma unroll
  for (int i = 0; i < 2; ++i)
    #pragma unroll
    for (int j = 0; j < 8; ++j) acc[i][j] = (f32x4){0.f, 0.f, 0.f, 0.f};

  for (int k0 = 0; k0 < 1024; k0 += 32) {
    // ---- stage A: X[128 rows][32 k] fp32 -> hi/lo bf16 ----
    float tmp[16];
    {
      const float4 v0 = *reinterpret_cast<const float4*>(&xrow[k0 + sk + 0]);
      const float4 v1 = *reinterpret_cast<const float4*>(&xrow[k0 + sk + 4]);
      const float4 v2 = *reinterpret_cast<const float4*>(&xrow[k0 + sk + 8]);
      const float4 v3 = *reinterpret_cast<const float4*>(&xrow[k0 + sk + 12]);
      tmp[0] = v0.x; tmp[1] = v0.y; tmp[2] = v0.z; tmp[3] = v0.w;
      tmp[4] = v1.x; tmp[5] = v1.y; tmp[6] = v1.z; tmp[7] = v1.w;
      tmp[8] = v2.x; tmp[9] = v2.y; tmp[10] = v2.z; tmp[11] = v2.w;
      tmp[12] = v3.x; tmp[13] = v3.y; tmp[14] = v3.z; tmp[15] = v3.w;
    }
    bf16x8 hv0, hv1, lv0, lv1;
    #pragma unroll
    for (int j = 0; j < 8; ++j) {
      __bf16 h = (__bf16)tmp[j];
      hv0[j] = h; lv0[j] = (__bf16)(tmp[j] - (float)h);
    }
    #pragma unroll
    for (int j = 0; j < 8; ++j) {
      __bf16 h = (__bf16)tmp[8 + j];
      hv1[j] = h; lv1[j] = (__bf16)(tmp[8 + j] - (float)h);
    }
    *reinterpret_cast<bf16x8*>(&Ah[sr * LDST + sk]) = hv0;
    *reinterpret_cast<bf16x8*>(&Ah[sr * LDST + sk + 8]) = hv1;
    *reinterpret_cast<bf16x8*>(&Al[sr * LDST + sk]) = lv0;
    *reinterpret_cast<bf16x8*>(&Al[sr * LDST + sk + 8]) = lv1;
    // ---- stage B: Wt rows already bf16 hi/lo, just copy 16 elems each ----
    {
      bf16x8 b0 = *reinterpret_cast<const bf16x8*>(&wthr[k0 + sk]);
      bf16x8 b1 = *reinterpret_cast<const bf16x8*>(&wthr[k0 + sk + 8]);
      bf16x8 c0 = *reinterpret_cast<const bf16x8*>(&wtlr[k0 + sk]);
      bf16x8 c1 = *reinterpret_cast<const bf16x8*>(&wtlr[k0 + sk + 8]);
      *reinterpret_cast<bf16x8*>(&Bh[sr * LDST + sk]) = b0;
      *reinterpret_cast<bf16x8*>(&Bh[sr * LDST + sk + 8]) = b1;
      *reinterpret_cast<bf16x8*>(&Bl[sr * LDST + sk]) = c0;
      *reinterpret_cast<bf16x8*>(&Bl[sr * LDST + sk + 8]) = c1;
    }
    __syncthreads();
    // ---- fragments + MFMA ----
    bf16x8 afh[2], afl[2];
    #pragma unroll
    for (int mt = 0; mt < 2; ++mt) {
      int r = wv * 32 + mt * 16 + lrow;
      afh[mt] = *reinterpret_cast<const bf16x8*>(&Ah[r * LDST + quad * 8]);
      afl[mt] = *reinterpret_cast<const bf16x8*>(&Al[r * LDST + quad * 8]);
    }
    #pragma unroll
    for (int nt = 0; nt < 8; ++nt) {
      int r = nt * 16 + lrow;
      bf16x8 bfh = *reinterpret_cast<const bf16x8*>(&Bh[r * LDST + quad * 8]);
      bf16x8 bfl = *reinterpret_cast<const bf16x8*>(&Bl[r * LDST + quad * 8]);
      #pragma unroll
      for (int mt = 0; mt < 2; ++mt) {
        acc[mt][nt] = __builtin_amdgcn_mfma_f32_16x16x32_bf16(afh[mt], bfh, acc[mt][nt], 0, 0, 0);
        acc[mt][nt] = __builtin_amdgcn_mfma_f32_16x16x32_bf16(afl[mt], bfh, acc[mt][nt], 0, 0, 0);
        acc[mt][nt] = __builtin_amdgcn_mfma_f32_16x16x32_bf16(afh[mt], bfl, acc[mt][nt], 0, 0, 0);
      }
    }
    __syncthreads();
  }
  // ---- epilogue: D[m][n]: n = lane&15, m = quad*4 + reg ----
  #pragma unroll
  for (int mt = 0; mt < 2; ++mt) {
    #pragma unroll
    for (int r = 0; r < 4; ++r) {
      int row = m0 + wv * 32 + mt * 16 + quad * 4 + r;
      if (row < M) {
        #pragma unroll
        for (int nt = 0; nt < 8; ++nt) {
          H1[(size_t)row * 128 + nt * 16 + lrow] = acc[mt][nt][r];
        }
      }
    }
  }
}

// ---------------- attention scalars layer 1 ----------------
__global__ __launch_bounds__(256) void a1_kernel(const float* __restrict__ h1, const float* __restrict__ att_s,
                                                 const float* __restrict__ att_d, float* __restrict__ a_src,
                                                 float* __restrict__ a_dst) {
  int idx = blockIdx.x * 256 + threadIdx.x;   // n*16 + h
  if (idx >= NN * NH) return;
  int h = idx & 15;
  const float* hp = &h1[(size_t)idx * 8];
  float s = 0.f, d = 0.f;
  #pragma unroll
  for (int c = 0; c < 8; ++c) {
    float v = hp[c];
    s += v * att_s[h * 8 + c];
    d += v * att_d[h * 8 + c];
  }
  a_src[idx] = s; a_dst[idx] = d;
}

// ---------------- layer1 aggregation: online softmax + ELU epilogue ----------------
__global__ __launch_bounds__(128) void agg1_kernel(const float* __restrict__ h1, const float* __restrict__ a_src,
                                                   const float* __restrict__ a_dst, const int* __restrict__ offs,
                                                   const int* __restrict__ csr, const float* __restrict__ b1,
                                                   float* __restrict__ act1) {
  int n = blockIdx.x;
  int t = threadIdx.x;        // channel 0..127
  int h = t >> 3;
  float adst = a_dst[n * NH + h];
  int beg = offs[n], end = offs[n + 1];
  float m = -INFINITY, l = 0.f, acc = 0.f;
  for (int e = beg; e < end; ++e) {
    int s = csr[e];
    float a = a_src[s * NH + h] + adst;
    a = a > 0.f ? a : 0.2f * a;
    float nm = fmaxf(m, a);
    float sc = __expf(m - nm);
    float w = __expf(a - nm);
    l = l * sc + w;
    acc = acc * sc + w * h1[(size_t)s * 128 + t];
    m = nm;
  }
  float o = acc / (l + 1e-16f) + b1[t];
  act1[(size_t)n * 128 + t] = o > 0.f ? o : expm1f(o);
}

// ---------------- GEMM2: h2 = act1 @ W2  (K=128, N=19) ----------------
__global__ __launch_bounds__(256) void gemm2_kernel(const float* __restrict__ A, const float* __restrict__ W2,
                                                    float* __restrict__ H2) {
  __shared__ float Ws[128 * 19];
  for (int i = threadIdx.x; i < 128 * 19; i += 256) Ws[i] = W2[i];
  __syncthreads();
  int idx = blockIdx.x * 256 + threadIdx.x;
  if (idx >= NN * F2) return;
  int row = idx / F2, col = idx % F2;
  const float* a = &A[(size_t)row * 128];
  float s = 0.f;
  #pragma unroll 8
  for (int k = 0; k < 128; ++k) s += a[k] * Ws[k * F2 + col];
  H2[idx] = s;
}

// ---------------- attention scalars layer 2 ----------------
__global__ __launch_bounds__(256) void a2_kernel(const float* __restrict__ h2, const float* __restrict__ att_s,
                                                 const float* __restrict__ att_d, float* __restrict__ a_src,
                                                 float* __restrict__ a_dst) {
  int n = blockIdx.x * 256 + threadIdx.x;
  if (n >= NN) return;
  const float* hp = &h2[(size_t)n * F2];
  float s = 0.f, d = 0.f;
  #pragma unroll
  for (int c = 0; c < F2; ++c) {
    float v = hp[c];
    s += v * att_s[c];
    d += v * att_d[c];
  }
  a_src[n] = s; a_dst[n] = d;
}

// ---------------- layer2 aggregation + bias + log_softmax ----------------
__global__ __launch_bounds__(64) void agg2_kernel(const float* __restrict__ h2, const float* __restrict__ a_src,
                                                  const float* __restrict__ a_dst, const int* __restrict__ offs,
                                                  const int* __restrict__ csr, const float* __restrict__ b2,
                                                  float* __restrict__ out) {
  int n = blockIdx.x;
  int t = threadIdx.x;
  bool act = t < F2;
  float adst = a_dst[n];
  int beg = offs[n], end = offs[n + 1];
  float m = -INFINITY, l = 0.f, acc = 0.f;
  for (int e = beg; e < end; ++e) {
    int s = csr[e];
    float a = a_src[s] + adst;
    a = a > 0.f ? a : 0.2f * a;
    float nm = fmaxf(m, a);
    float sc = __expf(m - nm);
    float w = __expf(a - nm);
    l = l * sc + w;
    float hv = act ? h2[(size_t)s * F2 + t] : 0.f;
    acc = acc * sc + w * hv;
    m = nm;
  }
  float o = acc / (l + 1e-16f) + (act ? b2[t] : 0.f);
  float v = act ? o : -INFINITY;
  float mx = v;
  #pragma unroll
  for (int off = 16; off >= 1; off >>= 1) mx = fmaxf(mx, __shfl_xor(mx, off, 64));
  float se = act ? __expf(v - mx) : 0.f;
  float sum = se;
  #pragma unroll
  for (int off = 16; off >= 1; off >>= 1) sum += __shfl_xor(sum, off, 64);
  if (act) out[(size_t)n * F2 + t] = (o - mx) - logf(sum);
}

extern "C" void kernel_launch(void* const* d_in, const int* in_sizes, int n_in,
                              void* d_out, int out_size, void* d_ws, size_t ws_size,
                              hipStream_t stream) {
  const float* x   = (const float*)d_in[0];
  const int* ei    = (const int*)d_in[1];
  const float* W1  = (const float*)d_in[2];
  const float* as1 = (const float*)d_in[3];
  const float* ad1 = (const float*)d_in[4];
  const float* b1  = (const float*)d_in[5];
  const float* W2  = (const float*)d_in[6];
  const float* as2 = (const float*)d_in[7];
  const float* ad2 = (const float*)d_in[8];
  const float* b2  = (const float*)d_in[9];
  float* out = (float*)d_out;

  const int* srcp = ei;
  const int* dstp = ei + EE;

  char* p = (char*)d_ws;
  auto alloc = [&](size_t bytes) { char* r = p; p += (bytes + 255) & ~(size_t)255; return r; };
  float* h1    = (float*)alloc((size_t)NN * F1 * 4);
  float* act1  = (float*)alloc((size_t)NN * F1 * 4);
  float* a_s1  = (float*)alloc((size_t)NN * NH * 4);
  float* a_d1  = (float*)alloc((size_t)NN * NH * 4);
  float* h2    = (float*)alloc((size_t)NN * F2 * 4);
  float* a_s2  = (float*)alloc((size_t)NN * 4);
  float* a_d2  = (float*)alloc((size_t)NN * 4);
  int*   deg   = (int*)alloc((size_t)NN * 4);
  int*   offs  = (int*)alloc((size_t)(NN + 1) * 4);
  int*   cnt   = (int*)alloc((size_t)NN * 4);
  int*   csr   = (int*)alloc((size_t)ET * 4);
  __bf16* Wth  = (__bf16*)alloc((size_t)128 * 1024 * 2);
  __bf16* Wtl  = (__bf16*)alloc((size_t)128 * 1024 * 2);

  hipMemsetAsync(deg, 0, (size_t)NN * 4, stream);
  hipMemsetAsync(cnt, 0, (size_t)NN * 4, stream);

  int eb = (ET + 255) / 256;
  deg_kernel<<<eb, 256, 0, stream>>>(dstp, deg);
  scan_kernel<<<1, 1024, 0, stream>>>(deg, offs);
  fill_kernel<<<eb, 256, 0, stream>>>(srcp, dstp, offs, cnt, csr);

  wsplit_kernel<<<(1024 * 128 + 255) / 256, 256, 0, stream>>>(W1, Wth, Wtl);
  gemm1_mfma<<<(NN + 127) / 128, 256, 0, stream>>>(x, Wth, Wtl, h1, NN);
  a1_kernel<<<(NN * NH + 255) / 256, 256, 0, stream>>>(h1, as1, ad1, a_s1, a_d1);
  agg1_kernel<<<NN, 128, 0, stream>>>(h1, a_s1, a_d1, offs, csr, b1, act1);

  gemm2_kernel<<<(NN * F2 + 255) / 256, 256, 0, stream>>>(act1, W2, h2);
  a2_kernel<<<(NN + 255) / 256, 256, 0, stream>>>(h2, as2, ad2, a_s2, a_d2);
  agg2_kernel<<<NN, 64, 0, stream>>>(h2, a_s2, a_d2, offs, csr, b2, out);
}

// Round 3
// 1106.456 us; speedup vs baseline: 1.2718x; 1.1282x over previous
//
#include <hip/hip_runtime.h>
#include <math.h>

#define NN 100000
#define EE 1600000
#define ET (EE + NN)   // edges + self loops
#define F1 128         // H*C layer1
#define NH 16
#define F2 19

typedef __bf16 bf16x8 __attribute__((ext_vector_type(8)));
typedef float f32x4 __attribute__((ext_vector_type(4)));

#define LDST 40   // LDS row stride in bf16 elems: 80B -> 16B aligned, 2-way bank alias (free)

// ---------------- CSR build ----------------
__global__ __launch_bounds__(256) void deg_kernel(const int* __restrict__ dst, int* __restrict__ deg) {
  int e = blockIdx.x * 256 + threadIdx.x;
  if (e >= ET) return;
  int d = (e < EE) ? dst[e] : (e - EE);
  atomicAdd(&deg[d], 1);
}

// ---- parallel exclusive scan over deg[NN] -> offs, 3 phases ----
#define SCB 391   // ceil(100000/256)
__global__ __launch_bounds__(256) void scan_block(const int* __restrict__ deg, int* __restrict__ offs,
                                                  int* __restrict__ bsum) {
  __shared__ int wsum[4];
  int b = blockIdx.x, tid = threadIdx.x;
  int i = b * 256 + tid;
  int lane = tid & 63, wid = tid >> 6;
  int v = (i < NN) ? deg[i] : 0;
  int x = v;
  #pragma unroll
  for (int off = 1; off < 64; off <<= 1) {
    int t = __shfl_up(x, off, 64);
    if (lane >= off) x += t;
  }
  if (lane == 63) wsum[wid] = x;
  __syncthreads();
  int add = 0;
  #pragma unroll
  for (int w = 0; w < 4; ++w) if (w < wid) add += wsum[w];
  if (i < NN) offs[i] = x + add - v;   // exclusive within block
  if (tid == 255) bsum[b] = x + add;
}

__global__ __launch_bounds__(512) void scan_tops(int* __restrict__ bsum, int* __restrict__ tops,
                                                 int* __restrict__ offs) {
  __shared__ int wsum[8];
  int tid = threadIdx.x;
  int lane = tid & 63, wid = tid >> 6;
  int v = (tid < SCB) ? bsum[tid] : 0;
  int x = v;
  #pragma unroll
  for (int off = 1; off < 64; off <<= 1) {
    int t = __shfl_up(x, off, 64);
    if (lane >= off) x += t;
  }
  if (lane == 63) wsum[wid] = x;
  __syncthreads();
  int add = 0;
  #pragma unroll
  for (int w = 0; w < 8; ++w) if (w < wid) add += wsum[w];
  if (tid < SCB) tops[tid] = x + add - v;   // exclusive scan of block sums
  if (tid == SCB - 1) offs[NN] = x + add;   // grand total == ET
}

__global__ __launch_bounds__(256) void scan_add(int* __restrict__ offs, const int* __restrict__ tops) {
  int i = blockIdx.x * 256 + threadIdx.x;
  if (i < NN) offs[i] += tops[blockIdx.x];
}

__global__ __launch_bounds__(256) void fill_kernel(const int* __restrict__ src, const int* __restrict__ dst,
                                                   const int* __restrict__ offs, int* __restrict__ cnt,
                                                   int* __restrict__ csr) {
  int e = blockIdx.x * 256 + threadIdx.x;
  if (e >= ET) return;
  int d, s;
  if (e < EE) { d = dst[e]; s = src[e]; } else { d = e - EE; s = e - EE; }
  int pos = offs[d] + atomicAdd(&cnt[d], 1);
  csr[pos] = s;
}

// ---------------- W1 split+transpose: Wt_h/Wt_l [128][1024] bf16 ----------------
__global__ __launch_bounds__(256) void wsplit_kernel(const float* __restrict__ W, __bf16* __restrict__ Wth,
                                                     __bf16* __restrict__ Wtl) {
  int idx = blockIdx.x * 256 + threadIdx.x;   // k*128 + n
  if (idx >= 1024 * 128) return;
  int k = idx >> 7, n = idx & 127;
  float v = W[idx];
  __bf16 h = (__bf16)v;
  __bf16 l = (__bf16)(v - (float)h);
  Wth[(size_t)n * 1024 + k] = h;
  Wtl[(size_t)n * 1024 + k] = l;
}

// ---------------- GEMM1: h1 = x @ W1 via bf16x3 MFMA (M=1e5, K=1024, N=128) ----------------
__global__ __launch_bounds__(256) void gemm1_mfma(const float* __restrict__ X, const __bf16* __restrict__ Wth,
                                                  const __bf16* __restrict__ Wtl, float* __restrict__ H1, int M) {
  __shared__ __bf16 Ah[128 * LDST];
  __shared__ __bf16 Al[128 * LDST];
  __shared__ __bf16 Bh[128 * LDST];
  __shared__ __bf16 Bl[128 * LDST];
  const int tid = threadIdx.x;
  const int m0 = blockIdx.x * 128;
  const int wv = tid >> 6, lane = tid & 63;
  const int lrow = lane & 15, quad = lane >> 4;
  const int sr = tid >> 1;
  const int sk = (tid & 1) * 16;
  int grow = m0 + sr; if (grow > M - 1) grow = M - 1;
  const float* xrow = &X[(size_t)grow * 1024];
  const __bf16* wthr = &Wth[(size_t)sr * 1024];
  const __bf16* wtlr = &Wtl[(size_t)sr * 1024];

  f32x4 acc[2][8];
  #pragma unroll
  for (int i = 0; i < 2; ++i)
    #pragma unroll
    for (int j = 0; j < 8; ++j) acc[i][j] = (f32x4){0.f, 0.f, 0.f, 0.f};

  for (int k0 = 0; k0 < 1024; k0 += 32) {
    float tmp[16];
    {
      const float4 v0 = *reinterpret_cast<const float4*>(&xrow[k0 + sk + 0]);
      const float4 v1 = *reinterpret_cast<const float4*>(&xrow[k0 + sk + 4]);
      const float4 v2 = *reinterpret_cast<const float4*>(&xrow[k0 + sk + 8]);
      const float4 v3 = *reinterpret_cast<const float4*>(&xrow[k0 + sk + 12]);
      tmp[0] = v0.x; tmp[1] = v0.y; tmp[2] = v0.z; tmp[3] = v0.w;
      tmp[4] = v1.x; tmp[5] = v1.y; tmp[6] = v1.z; tmp[7] = v1.w;
      tmp[8] = v2.x; tmp[9] = v2.y; tmp[10] = v2.z; tmp[11] = v2.w;
      tmp[12] = v3.x; tmp[13] = v3.y; tmp[14] = v3.z; tmp[15] = v3.w;
    }
    bf16x8 hv0, hv1, lv0, lv1;
    #pragma unroll
    for (int j = 0; j < 8; ++j) {
      __bf16 h = (__bf16)tmp[j];
      hv0[j] = h; lv0[j] = (__bf16)(tmp[j] - (float)h);
    }
    #pragma unroll
    for (int j = 0; j < 8; ++j) {
      __bf16 h = (__bf16)tmp[8 + j];
      hv1[j] = h; lv1[j] = (__bf16)(tmp[8 + j] - (float)h);
    }
    *reinterpret_cast<bf16x8*>(&Ah[sr * LDST + sk]) = hv0;
    *reinterpret_cast<bf16x8*>(&Ah[sr * LDST + sk + 8]) = hv1;
    *reinterpret_cast<bf16x8*>(&Al[sr * LDST + sk]) = lv0;
    *reinterpret_cast<bf16x8*>(&Al[sr * LDST + sk + 8]) = lv1;
    {
      bf16x8 b0 = *reinterpret_cast<const bf16x8*>(&wthr[k0 + sk]);
      bf16x8 b1 = *reinterpret_cast<const bf16x8*>(&wthr[k0 + sk + 8]);
      bf16x8 c0 = *reinterpret_cast<const bf16x8*>(&wtlr[k0 + sk]);
      bf16x8 c1 = *reinterpret_cast<const bf16x8*>(&wtlr[k0 + sk + 8]);
      *reinterpret_cast<bf16x8*>(&Bh[sr * LDST + sk]) = b0;
      *reinterpret_cast<bf16x8*>(&Bh[sr * LDST + sk + 8]) = b1;
      *reinterpret_cast<bf16x8*>(&Bl[sr * LDST + sk]) = c0;
      *reinterpret_cast<bf16x8*>(&Bl[sr * LDST + sk + 8]) = c1;
    }
    __syncthreads();
    bf16x8 afh[2], afl[2];
    #pragma unroll
    for (int mt = 0; mt < 2; ++mt) {
      int r = wv * 32 + mt * 16 + lrow;
      afh[mt] = *reinterpret_cast<const bf16x8*>(&Ah[r * LDST + quad * 8]);
      afl[mt] = *reinterpret_cast<const bf16x8*>(&Al[r * LDST + quad * 8]);
    }
    #pragma unroll
    for (int nt = 0; nt < 8; ++nt) {
      int r = nt * 16 + lrow;
      bf16x8 bfh = *reinterpret_cast<const bf16x8*>(&Bh[r * LDST + quad * 8]);
      bf16x8 bfl = *reinterpret_cast<const bf16x8*>(&Bl[r * LDST + quad * 8]);
      #pragma unroll
      for (int mt = 0; mt < 2; ++mt) {
        acc[mt][nt] = __builtin_amdgcn_mfma_f32_16x16x32_bf16(afh[mt], bfh, acc[mt][nt], 0, 0, 0);
        acc[mt][nt] = __builtin_amdgcn_mfma_f32_16x16x32_bf16(afl[mt], bfh, acc[mt][nt], 0, 0, 0);
        acc[mt][nt] = __builtin_amdgcn_mfma_f32_16x16x32_bf16(afh[mt], bfl, acc[mt][nt], 0, 0, 0);
      }
    }
    __syncthreads();
  }
  #pragma unroll
  for (int mt = 0; mt < 2; ++mt) {
    #pragma unroll
    for (int r = 0; r < 4; ++r) {
      int row = m0 + wv * 32 + mt * 16 + quad * 4 + r;
      if (row < M) {
        #pragma unroll
        for (int nt = 0; nt < 8; ++nt) {
          H1[(size_t)row * 128 + nt * 16 + lrow] = acc[mt][nt][r];
        }
      }
    }
  }
}

// ---------------- attention scalars layer 1 (float4 loads) ----------------
__global__ __launch_bounds__(256) void a1_kernel(const float* __restrict__ h1, const float* __restrict__ att_s,
                                                 const float* __restrict__ att_d, float* __restrict__ a_src,
                                                 float* __restrict__ a_dst) {
  int idx = blockIdx.x * 256 + threadIdx.x;   // n*16 + h
  if (idx >= NN * NH) return;
  int h = idx & 15;
  const float4 v0 = *reinterpret_cast<const float4*>(&h1[(size_t)idx * 8]);
  const float4 v1 = *reinterpret_cast<const float4*>(&h1[(size_t)idx * 8 + 4]);
  const float4 s0 = *reinterpret_cast<const float4*>(&att_s[h * 8]);
  const float4 s1 = *reinterpret_cast<const float4*>(&att_s[h * 8 + 4]);
  const float4 d0 = *reinterpret_cast<const float4*>(&att_d[h * 8]);
  const float4 d1 = *reinterpret_cast<const float4*>(&att_d[h * 8 + 4]);
  float s = v0.x * s0.x + v0.y * s0.y + v0.z * s0.z + v0.w * s0.w
          + v1.x * s1.x + v1.y * s1.y + v1.z * s1.z + v1.w * s1.w;
  float d = v0.x * d0.x + v0.y * d0.y + v0.z * d0.z + v0.w * d0.w
          + v1.x * d1.x + v1.y * d1.y + v1.z * d1.z + v1.w * d1.w;
  a_src[idx] = s; a_dst[idx] = d;
}

// ---------------- layer1 aggregation: wave-per-node, two-pass softmax ----------------
__global__ __launch_bounds__(256) void agg1_kernel(const float* __restrict__ h1, const float* __restrict__ a_src,
                                                   const float* __restrict__ a_dst, const int* __restrict__ offs,
                                                   const int* __restrict__ csr, const float* __restrict__ b1,
                                                   float* __restrict__ act1) {
  const int wid = threadIdx.x >> 6, lane = threadIdx.x & 63;
  const int n = blockIdx.x * 4 + wid;
  if (n >= NN) return;
  const int beg = offs[n], end = offs[n + 1];
  // ---- pass 1: per-head max; lane = (edge subgroup eg, head h16) ----
  const int h16 = lane & 15;
  const int eg = lane >> 4;
  const float adst_h = a_dst[n * NH + h16];
  float m = -INFINITY;
  for (int e = beg + eg; e < end; e += 4) {
    int s = csr[e];
    float a = a_src[s * NH + h16] + adst_h;
    a = a > 0.f ? a : 0.2f * a;
    m = fmaxf(m, a);
  }
  m = fmaxf(m, __shfl_xor(m, 16, 64));
  m = fmaxf(m, __shfl_xor(m, 32, 64));
  // ---- pass 2: lane owns channels 2l,2l+1; head = lane>>2 ----
  const int h = lane >> 2;
  const float mh = __shfl(m, h, 64);        // lane h holds max of head h
  const float adst2 = __shfl(adst_h, h, 64);
  const int c2 = lane * 2;
  float2 acc0 = {0.f, 0.f}, acc1 = {0.f, 0.f};
  float ls0 = 0.f, ls1 = 0.f;
  int e = beg;
  for (; e + 1 < end; e += 2) {
    int s0 = csr[e], s1 = csr[e + 1];
    float a0 = a_src[s0 * NH + h] + adst2;
    float a1 = a_src[s1 * NH + h] + adst2;
    a0 = a0 > 0.f ? a0 : 0.2f * a0;
    a1 = a1 > 0.f ? a1 : 0.2f * a1;
    float w0 = __expf(a0 - mh);
    float w1 = __expf(a1 - mh);
    float2 hv0 = *reinterpret_cast<const float2*>(&h1[(size_t)s0 * 128 + c2]);
    float2 hv1 = *reinterpret_cast<const float2*>(&h1[(size_t)s1 * 128 + c2]);
    ls0 += w0; ls1 += w1;
    acc0.x += w0 * hv0.x; acc0.y += w0 * hv0.y;
    acc1.x += w1 * hv1.x; acc1.y += w1 * hv1.y;
  }
  if (e < end) {
    int s0 = csr[e];
    float a0 = a_src[s0 * NH + h] + adst2;
    a0 = a0 > 0.f ? a0 : 0.2f * a0;
    float w0 = __expf(a0 - mh);
    float2 hv0 = *reinterpret_cast<const float2*>(&h1[(size_t)s0 * 128 + c2]);
    ls0 += w0;
    acc0.x += w0 * hv0.x; acc0.y += w0 * hv0.y;
  }
  float lsum = ls0 + ls1;
  float inv = 1.f / (lsum + 1e-16f);
  float ox = (acc0.x + acc1.x) * inv + b1[c2];
  float oy = (acc0.y + acc1.y) * inv + b1[c2 + 1];
  float2 o;
  o.x = ox > 0.f ? ox : expm1f(ox);
  o.y = oy > 0.f ? oy : expm1f(oy);
  *reinterpret_cast<float2*>(&act1[(size_t)n * 128 + c2]) = o;
}

// ---------------- GEMM2: h2 = act1 @ W2  (K=128, N=19) ----------------
__global__ __launch_bounds__(256) void gemm2_kernel(const float* __restrict__ A, const float* __restrict__ W2,
                                                    float* __restrict__ H2) {
  __shared__ float Ws[128 * 19];
  for (int i = threadIdx.x; i < 128 * 19; i += 256) Ws[i] = W2[i];
  __syncthreads();
  int idx = blockIdx.x * 256 + threadIdx.x;
  if (idx >= NN * F2) return;
  int row = idx / F2, col = idx % F2;
  const float* a = &A[(size_t)row * 128];
  float s = 0.f;
  #pragma unroll 8
  for (int k = 0; k < 128; ++k) s += a[k] * Ws[k * F2 + col];
  H2[idx] = s;
}

// ---------------- attention scalars layer 2 ----------------
__global__ __launch_bounds__(256) void a2_kernel(const float* __restrict__ h2, const float* __restrict__ att_s,
                                                 const float* __restrict__ att_d, float* __restrict__ a_src,
                                                 float* __restrict__ a_dst) {
  int n = blockIdx.x * 256 + threadIdx.x;
  if (n >= NN) return;
  const float* hp = &h2[(size_t)n * F2];
  float s = 0.f, d = 0.f;
  #pragma unroll
  for (int c = 0; c < F2; ++c) {
    float v = hp[c];
    s += v * att_s[c];
    d += v * att_d[c];
  }
  a_src[n] = s; a_dst[n] = d;
}

// ---------------- layer2 aggregation + bias + log_softmax: wave-per-node ----------------
__global__ __launch_bounds__(256) void agg2_kernel(const float* __restrict__ h2, const float* __restrict__ a_src,
                                                   const float* __restrict__ a_dst, const int* __restrict__ offs,
                                                   const int* __restrict__ csr, const float* __restrict__ b2,
                                                   float* __restrict__ out) {
  const int wid = threadIdx.x >> 6, lane = threadIdx.x & 63;
  const int n = blockIdx.x * 4 + wid;
  if (n >= NN) return;
  const int beg = offs[n], end = offs[n + 1];
  const float adst = a_dst[n];
  // ---- pass 1: max over edges (64-way parallel) ----
  float m = -INFINITY;
  for (int e = beg + lane; e < end; e += 64) {
    float a = a_src[csr[e]] + adst;
    a = a > 0.f ? a : 0.2f * a;
    m = fmaxf(m, a);
  }
  #pragma unroll
  for (int off = 32; off >= 1; off >>= 1) m = fmaxf(m, __shfl_xor(m, off, 64));
  // ---- pass 2: lanes 0..56 = (group g=lane/19, channel c=lane%19), 3 edges/step ----
  const int g = lane / 19;          // 0..3 (g==3 idle)
  const int c = lane - g * 19;
  float acc = 0.f, ls = 0.f;
  if (g < 3) {
    for (int e = beg + g; e < end; e += 3) {
      int s = csr[e];
      float a = a_src[s] + adst;
      a = a > 0.f ? a : 0.2f * a;
      float w = __expf(a - m);
      ls += w;
      acc += w * h2[(size_t)s * F2 + c];
    }
  }
  // merge the 3 groups: lane c collects from lanes c, c+19, c+38
  float acc_t = __shfl(acc, c, 64) + __shfl(acc, c + 19, 64) + __shfl(acc, c + 38, 64);
  float ls_t  = __shfl(ls, c, 64) + __shfl(ls, c + 19, 64) + __shfl(ls, c + 38, 64);
  const bool act = lane < F2;
  float o = acc_t / (ls_t + 1e-16f) + (act ? b2[lane] : 0.f);
  // log_softmax across lanes 0..18 (use lanes 0..31 reduce)
  float v = act ? o : -INFINITY;
  float mx = v;
  #pragma unroll
  for (int off = 16; off >= 1; off >>= 1) mx = fmaxf(mx, __shfl_xor(mx, off, 32));
  float se = act ? __expf(v - mx) : 0.f;
  float sum = se;
  #pragma unroll
  for (int off = 16; off >= 1; off >>= 1) sum += __shfl_xor(sum, off, 32);
  if (act) out[(size_t)n * F2 + lane] = (o - mx) - logf(sum);
}

extern "C" void kernel_launch(void* const* d_in, const int* in_sizes, int n_in,
                              void* d_out, int out_size, void* d_ws, size_t ws_size,
                              hipStream_t stream) {
  const float* x   = (const float*)d_in[0];
  const int* ei    = (const int*)d_in[1];
  const float* W1  = (const float*)d_in[2];
  const float* as1 = (const float*)d_in[3];
  const float* ad1 = (const float*)d_in[4];
  const float* b1  = (const float*)d_in[5];
  const float* W2  = (const float*)d_in[6];
  const float* as2 = (const float*)d_in[7];
  const float* ad2 = (const float*)d_in[8];
  const float* b2  = (const float*)d_in[9];
  float* out = (float*)d_out;

  const int* srcp = ei;
  const int* dstp = ei + EE;

  char* p = (char*)d_ws;
  auto alloc = [&](size_t bytes) { char* r = p; p += (bytes + 255) & ~(size_t)255; return r; };
  float* h1    = (float*)alloc((size_t)NN * F1 * 4);
  float* act1  = (float*)alloc((size_t)NN * F1 * 4);
  float* a_s1  = (float*)alloc((size_t)NN * NH * 4);
  float* a_d1  = (float*)alloc((size_t)NN * NH * 4);
  float* h2    = (float*)alloc((size_t)NN * F2 * 4);
  float* a_s2  = (float*)alloc((size_t)NN * 4);
  float* a_d2  = (float*)alloc((size_t)NN * 4);
  int*   deg   = (int*)alloc((size_t)NN * 4);
  int*   offs  = (int*)alloc((size_t)(NN + 1) * 4);
  int*   cnt   = (int*)alloc((size_t)NN * 4);
  int*   csr   = (int*)alloc((size_t)ET * 4);
  int*   bsum  = (int*)alloc((size_t)SCB * 4);
  int*   tops  = (int*)alloc((size_t)SCB * 4);
  __bf16* Wth  = (__bf16*)alloc((size_t)128 * 1024 * 2);
  __bf16* Wtl  = (__bf16*)alloc((size_t)128 * 1024 * 2);

  hipMemsetAsync(deg, 0, (size_t)NN * 4, stream);
  hipMemsetAsync(cnt, 0, (size_t)NN * 4, stream);

  int eb = (ET + 255) / 256;
  deg_kernel<<<eb, 256, 0, stream>>>(dstp, deg);
  scan_block<<<SCB, 256, 0, stream>>>(deg, offs, bsum);
  scan_tops<<<1, 512, 0, stream>>>(bsum, tops, offs);
  scan_add<<<SCB, 256, 0, stream>>>(offs, tops);
  fill_kernel<<<eb, 256, 0, stream>>>(srcp, dstp, offs, cnt, csr);

  wsplit_kernel<<<(1024 * 128 + 255) / 256, 256, 0, stream>>>(W1, Wth, Wtl);
  gemm1_mfma<<<(NN + 127) / 128, 256, 0, stream>>>(x, Wth, Wtl, h1, NN);
  a1_kernel<<<(NN * NH + 255) / 256, 256, 0, stream>>>(h1, as1, ad1, a_s1, a_d1);
  agg1_kernel<<<(NN + 3) / 4, 256, 0, stream>>>(h1, a_s1, a_d1, offs, csr, b1, act1);

  gemm2_kernel<<<(NN * F2 + 255) / 256, 256, 0, stream>>>(act1, W2, h2);
  a2_kernel<<<(NN + 255) / 256, 256, 0, stream>>>(h2, as2, ad2, a_s2, a_d2);
  agg2_kernel<<<(NN + 3) / 4, 256, 0, stream>>>(h2, a_s2, a_d2, offs, csr, b2, out);
}